// Round 6
// baseline (207.988 us; speedup 1.0000x reference)
//
#include <hip/hip_runtime.h>

// Problem constants (compile-time)
#define BB   16
#define CIN  64
#define NF   257
#define NT   512
#define T4   (NT/4)          // 128 float4 per row
#define FT4  (NF*T4)         // 32896 float4 per channel plane
#define NBLK 1028            // blocks; each handles 2 tiles of 256 float4-pixels

__device__ __forceinline__ float4 f4(float v) { return make_float4(v, v, v, v); }

__device__ __forceinline__ void fma4(float4& a, float w, const float4& x) {
    a.x = fmaf(w, x.x, a.x); a.y = fmaf(w, x.y, a.y);
    a.z = fmaf(w, x.z, a.z); a.w = fmaf(w, x.w, a.w);
}
__device__ __forceinline__ float4 relu4(float4 a) {
    return make_float4(fmaxf(a.x, 0.f), fmaxf(a.y, 0.f), fmaxf(a.z, 0.f), fmaxf(a.w, 0.f));
}
__device__ __forceinline__ float ssign1(float x) { return x / (1.f + fabsf(x)); }
__device__ __forceinline__ float4 ssign4(float4 a) {
    return make_float4(ssign1(a.x), ssign1(a.y), ssign1(a.z), ssign1(a.w));
}
__device__ __forceinline__ float sigm1(float x) { return 1.f / (1.f + __expf(-x)); }
__device__ __forceinline__ float4 sigm4(float4 a) {
    return make_float4(sigm1(a.x), sigm1(a.y), sigm1(a.z), sigm1(a.w));
}
__device__ __forceinline__ float4 mul4(float4 a, float4 b) {
    return make_float4(a.x * b.x, a.y * b.y, a.z * b.z, a.w * b.w);
}
__device__ __forceinline__ float4 fma44(float4 a, float4 b, float4 c) {
    return make_float4(fmaf(a.x, b.x, c.x), fmaf(a.y, b.y, c.y),
                       fmaf(a.z, b.z, c.z), fmaf(a.w, b.w, c.w));
}

// One FMA block of conv1 for channel c with input vector x
#define C1STEP(c, x)                                                              \
    {                                                                             \
        float4 wA = sW14[(c) * 3 + 0];                                            \
        float4 wB = sW14[(c) * 3 + 1];                                            \
        float4 wC = sW14[(c) * 3 + 2];                                            \
        fma4(h[0], wA.x, (x)); fma4(h[1], wA.y, (x));                             \
        fma4(h[2], wA.z, (x)); fma4(h[3], wA.w, (x));                             \
        fma4(h[4], wB.x, (x)); fma4(h[5], wB.y, (x));                             \
        fma4(h[6], wB.z, (x)); fma4(h[7], wB.w, (x));                             \
        fma4(h[8], wC.x, (x)); fma4(h[9], wC.y, (x));                             \
        fma4(h[10], wC.z, (x));                                                   \
    }

__global__ __launch_bounds__(256) void outconv_fused(
    const float* __restrict__ xdec,   // [B,64,F,T]
    const float* __restrict__ xskip,  // [B,4,F,T]
    const float* __restrict__ W1,     // [11,64]
    const float* __restrict__ b1,     // [11]
    const float* __restrict__ W2,     // [11,15]
    const float* __restrict__ b2,     // [11]
    float* __restrict__ out)          // [B,4,F,T]
{
    // sW14[c*3 + j] holds W1[4j..4j+3][c] (transposed, row 11 padded 0)
    __shared__ float4 sW14[CIN * 3];
    // sW2r[k*4 + j] holds W2[k][4j..4j+3] (row-major, padded to 16 cols)
    __shared__ float4 sW2r[11 * 4];
    __shared__ float  sB1[11];
    __shared__ float  sB2[11];

    {
        float* s = (float*)sW14;
        for (int i = threadIdx.x; i < CIN * 12; i += 256) {
            int c = i / 12, o = i - c * 12;
            s[i] = (o < 11) ? W1[o * CIN + c] : 0.f;
        }
        float* s2 = (float*)sW2r;
        for (int i = threadIdx.x; i < 11 * 16; i += 256) {
            int k = i >> 4, c = i & 15;
            s2[i] = (c < 15) ? W2[k * 15 + c] : 0.f;
        }
        if (threadIdx.x < 11) {
            sB1[threadIdx.x] = b1[threadIdx.x];
            sB2[threadIdx.x] = b2[threadIdx.x];
        }
    }
    __syncthreads();

    #pragma unroll 1
    for (int tile = 0; tile < 2; ++tile) {
        const int v  = (blockIdx.x + tile * NBLK) * 256 + threadIdx.x;  // float4-pixel index
        const int t4 = v & (T4 - 1);
        const int bf = v >> 7;          // b*NF + f
        const int f  = bf % NF;
        const int b  = bf / NF;

        const float4* xd4 = (const float4*)xdec  + (size_t)b * CIN * FT4 + (size_t)f * T4 + t4;
        const float4* xs4 = (const float4*)xskip + (size_t)b * 4   * FT4 + (size_t)f * T4 + t4;
        float4*       o4  = (float4*)out         + (size_t)b * 4   * FT4 + (size_t)f * T4 + t4;

        // Skip channels (issued early; consumed in conv2)
        float4 s0 = xs4[0];
        float4 s1 = xs4[FT4];
        float4 s2 = xs4[2 * FT4];
        float4 s3 = xs4[3 * FT4];

        // Rolling 8-deep prefetch ring (identical to R5's proven conv1)
        float4 buf[8];
        #pragma unroll
        for (int j = 0; j < 8; ++j) buf[j] = xd4[(size_t)j * FT4];

        float4 h[11];
        #pragma unroll
        for (int o = 0; o < 11; ++o) h[o] = f4(sB1[o]);

        #pragma unroll 8
        for (int c = 0; c < 56; ++c) {
            float4 x = buf[c & 7];
            buf[c & 7] = xd4[(size_t)(c + 8) * FT4];
            C1STEP(c, x)
        }
        #pragma unroll
        for (int c = 56; c < 64; ++c) {
            float4 x = buf[c & 7];
            C1STEP(c, x)
        }

        #pragma unroll
        for (int o = 0; o < 11; ++o) h[o] = relu4(h[o]);

        // conv2 incremental: compute each output row k, consume immediately.
        float4 y0 = f4(0.f), y1 = f4(0.f), y2 = f4(0.f);
        float4 m0 = f4(0.f), m1 = f4(0.f);

        #pragma unroll
        for (int k = 0; k < 11; ++k) {
            float4 wA = sW2r[k * 4 + 0];
            float4 wB = sW2r[k * 4 + 1];
            float4 wC = sW2r[k * 4 + 2];
            float4 wD = sW2r[k * 4 + 3];
            float4 acc = f4(sB2[k]);
            fma4(acc, wA.x, s0);   fma4(acc, wA.y, s1);   fma4(acc, wA.z, s2);   fma4(acc, wA.w, s3);
            fma4(acc, wB.x, h[0]); fma4(acc, wB.y, h[1]); fma4(acc, wB.z, h[2]); fma4(acc, wB.w, h[3]);
            fma4(acc, wC.x, h[4]); fma4(acc, wC.y, h[5]); fma4(acc, wC.z, h[6]); fma4(acc, wC.w, h[7]);
            fma4(acc, wD.x, h[8]); fma4(acc, wD.y, h[9]); fma4(acc, wD.z, h[10]);
            if (k < 9) {
                float4 t = ssign4(acc);
                const int g = k / 3, c = k % 3;
                float4 sv = (c == 0) ? s0 : (c == 1) ? s1 : s2;
                if      (g == 0) y0 = fma44(t, sv, y0);
                else if (g == 1) y1 = fma44(t, sv, y1);
                else             y2 = fma44(t, sv, y2);
            } else if (k == 9) {
                m0 = sigm4(acc);
            } else {
                m1 = sigm4(acc);
            }
        }

        o4[0]       = mul4(m0, y0);
        o4[FT4]     = mul4(m0, y1);
        o4[2 * FT4] = mul4(m0, y2);
        o4[3 * FT4] = mul4(m1, s3);
    }
}

extern "C" void kernel_launch(void* const* d_in, const int* in_sizes, int n_in,
                              void* d_out, int out_size, void* d_ws, size_t ws_size,
                              hipStream_t stream) {
    const float* xdec  = (const float*)d_in[0];
    const float* xskip = (const float*)d_in[1];
    const float* W1    = (const float*)d_in[2];
    const float* b1    = (const float*)d_in[3];
    const float* W2    = (const float*)d_in[4];
    const float* b2    = (const float*)d_in[5];
    float* outp = (float*)d_out;

    // 2056 tiles of 256 float4-pixels; 1028 blocks x 2 tiles
    outconv_fused<<<NBLK, 256, 0, stream>>>(xdec, xskip, W1, b1, W2, b2, outp);
}

// Round 7
// 113.117 us; speedup vs baseline: 1.8387x; 1.8387x over previous
//
#include <hip/hip_runtime.h>

// Problem constants (compile-time)
#define BB   16
#define CIN  64
#define NF   257
#define NT   512
#define T4   (NT/4)          // 128 float4 per row
#define FT4  (NF*T4)         // 32896 float4 per channel plane

typedef float v4f __attribute__((ext_vector_type(4)));

__device__ __forceinline__ float4 ntload4(const float4* p) {
    v4f v = __builtin_nontemporal_load((const v4f*)p);
    return make_float4(v.x, v.y, v.z, v.w);
}
__device__ __forceinline__ void ntstore4(float4* p, float4 val) {
    v4f v;
    v.x = val.x; v.y = val.y; v.z = val.z; v.w = val.w;
    __builtin_nontemporal_store(v, (v4f*)p);
}

__device__ __forceinline__ float4 f4(float v) { return make_float4(v, v, v, v); }

__device__ __forceinline__ void fma4(float4& a, float w, const float4& x) {
    a.x = fmaf(w, x.x, a.x); a.y = fmaf(w, x.y, a.y);
    a.z = fmaf(w, x.z, a.z); a.w = fmaf(w, x.w, a.w);
}
__device__ __forceinline__ float4 relu4(float4 a) {
    return make_float4(fmaxf(a.x, 0.f), fmaxf(a.y, 0.f), fmaxf(a.z, 0.f), fmaxf(a.w, 0.f));
}
__device__ __forceinline__ float ssign1(float x) { return x / (1.f + fabsf(x)); }
__device__ __forceinline__ float4 ssign4(float4 a) {
    return make_float4(ssign1(a.x), ssign1(a.y), ssign1(a.z), ssign1(a.w));
}
__device__ __forceinline__ float sigm1(float x) { return 1.f / (1.f + __expf(-x)); }
__device__ __forceinline__ float4 sigm4(float4 a) {
    return make_float4(sigm1(a.x), sigm1(a.y), sigm1(a.z), sigm1(a.w));
}
__device__ __forceinline__ float4 mul4(float4 a, float4 b) {
    return make_float4(a.x * b.x, a.y * b.y, a.z * b.z, a.w * b.w);
}
__device__ __forceinline__ float4 fma44(float4 a, float4 b, float4 c) {
    return make_float4(fmaf(a.x, b.x, c.x), fmaf(a.y, b.y, c.y),
                       fmaf(a.z, b.z, c.z), fmaf(a.w, b.w, c.w));
}

// One FMA block of conv1 for channel c with input vector x
#define C1STEP(c, x)                                                              \
    {                                                                             \
        float4 wA = sW14[(c) * 3 + 0];                                            \
        float4 wB = sW14[(c) * 3 + 1];                                            \
        float4 wC = sW14[(c) * 3 + 2];                                            \
        fma4(h[0], wA.x, (x)); fma4(h[1], wA.y, (x));                             \
        fma4(h[2], wA.z, (x)); fma4(h[3], wA.w, (x));                             \
        fma4(h[4], wB.x, (x)); fma4(h[5], wB.y, (x));                             \
        fma4(h[6], wB.z, (x)); fma4(h[7], wB.w, (x));                             \
        fma4(h[8], wC.x, (x)); fma4(h[9], wC.y, (x));                             \
        fma4(h[10], wC.z, (x));                                                   \
    }

__global__ __launch_bounds__(256) void outconv_fused(
    const float* __restrict__ xdec,   // [B,64,F,T]
    const float* __restrict__ xskip,  // [B,4,F,T]
    const float* __restrict__ W1,     // [11,64]
    const float* __restrict__ b1,     // [11]
    const float* __restrict__ W2,     // [11,15]
    const float* __restrict__ b2,     // [11]
    float* __restrict__ out)          // [B,4,F,T]
{
    // Weights transposed into LDS: sW14[c*3 + j] holds W1[4j..4j+3][c] (row 11 padded 0)
    __shared__ float4 sW14[CIN * 3];
    __shared__ float4 sW24[15 * 3];
    __shared__ float  sB1[12];
    __shared__ float  sB2[12];

    {
        float* s = (float*)sW14;
        for (int i = threadIdx.x; i < CIN * 12; i += 256) {
            int c = i / 12, o = i - c * 12;
            s[i] = (o < 11) ? W1[o * CIN + c] : 0.f;
        }
        float* s2 = (float*)sW24;
        for (int i = threadIdx.x; i < 15 * 12; i += 256) {
            int c = i / 12, o = i - c * 12;
            s2[i] = (o < 11) ? W2[o * 15 + c] : 0.f;
        }
        if (threadIdx.x < 12) {
            int o = threadIdx.x;
            sB1[o] = (o < 11) ? b1[o] : 0.f;
            sB2[o] = (o < 11) ? b2[o] : 0.f;
        }
    }
    __syncthreads();

    const int v  = blockIdx.x * 256 + threadIdx.x;  // float4-pixel index
    const int t4 = v & (T4 - 1);
    const int bf = v >> 7;          // b*NF + f
    const int f  = bf % NF;
    const int b  = bf / NF;

    const float4* xd4 = (const float4*)xdec  + (size_t)b * CIN * FT4 + (size_t)f * T4 + t4;
    const float4* xs4 = (const float4*)xskip + (size_t)b * 4   * FT4 + (size_t)f * T4 + t4;
    float4*       o4  = (float4*)out         + (size_t)b * 4   * FT4 + (size_t)f * T4 + t4;

    // Skip channels (issued early; consumed in conv2) — non-temporal, zero reuse
    float4 s0 = ntload4(xs4);
    float4 s1 = ntload4(xs4 + FT4);
    float4 s2 = ntload4(xs4 + 2 * FT4);
    float4 s3 = ntload4(xs4 + 3 * FT4);

    // Rolling 8-deep prefetch ring: keeps ~8 loads continuously outstanding
    float4 buf[8];
    #pragma unroll
    for (int j = 0; j < 8; ++j) buf[j] = ntload4(xd4 + (size_t)j * FT4);

    // conv1: h[o] = relu(b1[o] + sum_c W1[o,c] * xd[c])
    float4 h[11];
    #pragma unroll
    for (int o = 0; o < 11; ++o) h[o] = f4(sB1[o]);

    // c = 0..55: consume buf[c&7], immediately refill with c+8 (static ring indices)
    #pragma unroll 8
    for (int c = 0; c < 56; ++c) {
        float4 x = buf[c & 7];
        buf[c & 7] = ntload4(xd4 + (size_t)(c + 8) * FT4);
        C1STEP(c, x)
    }
    // c = 56..63: drain
    #pragma unroll
    for (int c = 56; c < 64; ++c) {
        float4 x = buf[c & 7];
        C1STEP(c, x)
    }

    #pragma unroll
    for (int o = 0; o < 11; ++o) h[o] = relu4(h[o]);

    // conv2: out[o] = b2[o] + sum_{c<4} W2[o,c]*skip[c] + sum_j W2[o,4+j]*h[j]
    float4 o2[11];
    #pragma unroll
    for (int o = 0; o < 11; ++o) o2[o] = f4(sB2[o]);

#define W2COL(cidx, xvec)                                                         \
    {                                                                             \
        float4 wA = sW24[(cidx) * 3 + 0];                                         \
        float4 wB = sW24[(cidx) * 3 + 1];                                         \
        float4 wC = sW24[(cidx) * 3 + 2];                                         \
        fma4(o2[0], wA.x, xvec); fma4(o2[1], wA.y, xvec);                         \
        fma4(o2[2], wA.z, xvec); fma4(o2[3], wA.w, xvec);                         \
        fma4(o2[4], wB.x, xvec); fma4(o2[5], wB.y, xvec);                         \
        fma4(o2[6], wB.z, xvec); fma4(o2[7], wB.w, xvec);                         \
        fma4(o2[8], wC.x, xvec); fma4(o2[9], wC.y, xvec);                         \
        fma4(o2[10], wC.z, xvec);                                                 \
    }

    W2COL(0, s0)
    W2COL(1, s1)
    W2COL(2, s2)
    W2COL(3, s3)
    #pragma unroll
    for (int j = 0; j < 11; ++j) W2COL(4 + j, h[j])
#undef W2COL

    // activations + grouped contraction
    float4 m0 = sigm4(o2[9]);
    float4 m1 = sigm4(o2[10]);

    float4 y0 = mul4(m0, fma44(ssign4(o2[0]), s0, fma44(ssign4(o2[1]), s1, mul4(ssign4(o2[2]), s2))));
    float4 y1 = mul4(m0, fma44(ssign4(o2[3]), s0, fma44(ssign4(o2[4]), s1, mul4(ssign4(o2[5]), s2))));
    float4 y2 = mul4(m0, fma44(ssign4(o2[6]), s0, fma44(ssign4(o2[7]), s1, mul4(ssign4(o2[8]), s2))));
    float4 y3 = mul4(m1, s3);

    ntstore4(o4,           y0);
    ntstore4(o4 + FT4,     y1);
    ntstore4(o4 + 2 * FT4, y2);
    ntstore4(o4 + 3 * FT4, y3);
}

extern "C" void kernel_launch(void* const* d_in, const int* in_sizes, int n_in,
                              void* d_out, int out_size, void* d_ws, size_t ws_size,
                              hipStream_t stream) {
    const float* xdec  = (const float*)d_in[0];
    const float* xskip = (const float*)d_in[1];
    const float* W1    = (const float*)d_in[2];
    const float* b1    = (const float*)d_in[3];
    const float* W2    = (const float*)d_in[4];
    const float* b2    = (const float*)d_in[5];
    float* outp = (float*)d_out;

    const int total_v = BB * NF * T4;      // 526336
    const int blocks  = total_v / 256;     // 2056 exact
    outconv_fused<<<blocks, 256, 0, stream>>>(xdec, xskip, W1, b1, W2, b2, outp);
}

// Round 8
// 111.393 us; speedup vs baseline: 1.8672x; 1.0155x over previous
//
#include <hip/hip_runtime.h>

// Problem constants (compile-time)
#define BB   16
#define CIN  64
#define NF   257
#define NT   512
#define T4   (NT/4)          // 128 float4 per row
#define FT4  (NF*T4)         // 32896 float4 per channel plane

typedef float v4f __attribute__((ext_vector_type(4)));

__device__ __forceinline__ float4 ntload4(const float4* p) {
    v4f v = __builtin_nontemporal_load((const v4f*)p);
    return make_float4(v.x, v.y, v.z, v.w);
}
__device__ __forceinline__ void ntstore4(float4* p, float4 val) {
    v4f v;
    v.x = val.x; v.y = val.y; v.z = val.z; v.w = val.w;
    __builtin_nontemporal_store(v, (v4f*)p);
}

__device__ __forceinline__ float4 f4(float v) { return make_float4(v, v, v, v); }

__device__ __forceinline__ void fma4(float4& a, float w, const float4& x) {
    a.x = fmaf(w, x.x, a.x); a.y = fmaf(w, x.y, a.y);
    a.z = fmaf(w, x.z, a.z); a.w = fmaf(w, x.w, a.w);
}
__device__ __forceinline__ float4 relu4(float4 a) {
    return make_float4(fmaxf(a.x, 0.f), fmaxf(a.y, 0.f), fmaxf(a.z, 0.f), fmaxf(a.w, 0.f));
}
__device__ __forceinline__ float ssign1(float x) { return x / (1.f + fabsf(x)); }
__device__ __forceinline__ float4 ssign4(float4 a) {
    return make_float4(ssign1(a.x), ssign1(a.y), ssign1(a.z), ssign1(a.w));
}
__device__ __forceinline__ float sigm1(float x) { return 1.f / (1.f + __expf(-x)); }
__device__ __forceinline__ float4 sigm4(float4 a) {
    return make_float4(sigm1(a.x), sigm1(a.y), sigm1(a.z), sigm1(a.w));
}
__device__ __forceinline__ float4 mul4(float4 a, float4 b) {
    return make_float4(a.x * b.x, a.y * b.y, a.z * b.z, a.w * b.w);
}
__device__ __forceinline__ float4 fma44(float4 a, float4 b, float4 c) {
    return make_float4(fmaf(a.x, b.x, c.x), fmaf(a.y, b.y, c.y),
                       fmaf(a.z, b.z, c.z), fmaf(a.w, b.w, c.w));
}

// One FMA block of conv1 for channel c with input vector x.
// Weights read via lane-uniform addresses -> scalar loads (s_load), SGPR operands.
#define C1STEP(c, x)                                                              \
    {                                                                             \
        fma4(h[0],  W1[0 * CIN + (c)], (x));                                      \
        fma4(h[1],  W1[1 * CIN + (c)], (x));                                      \
        fma4(h[2],  W1[2 * CIN + (c)], (x));                                      \
        fma4(h[3],  W1[3 * CIN + (c)], (x));                                      \
        fma4(h[4],  W1[4 * CIN + (c)], (x));                                      \
        fma4(h[5],  W1[5 * CIN + (c)], (x));                                      \
        fma4(h[6],  W1[6 * CIN + (c)], (x));                                      \
        fma4(h[7],  W1[7 * CIN + (c)], (x));                                      \
        fma4(h[8],  W1[8 * CIN + (c)], (x));                                      \
        fma4(h[9],  W1[9 * CIN + (c)], (x));                                      \
        fma4(h[10], W1[10 * CIN + (c)], (x));                                     \
    }

__global__ __launch_bounds__(256) void outconv_fused(
    const float* __restrict__ xdec,   // [B,64,F,T]
    const float* __restrict__ xskip,  // [B,4,F,T]
    const float* __restrict__ W1,     // [11,64]
    const float* __restrict__ b1,     // [11]
    const float* __restrict__ W2,     // [11,15]
    const float* __restrict__ b2,     // [11]
    float* __restrict__ out)          // [B,4,F,T]
{
    const int v  = blockIdx.x * 256 + threadIdx.x;  // float4-pixel index
    const int t4 = v & (T4 - 1);
    const int bf = v >> 7;          // b*NF + f
    const int f  = bf % NF;
    const int b  = bf / NF;

    const float4* xd4 = (const float4*)xdec  + (size_t)b * CIN * FT4 + (size_t)f * T4 + t4;
    const float4* xs4 = (const float4*)xskip + (size_t)b * 4   * FT4 + (size_t)f * T4 + t4;
    float4*       o4  = (float4*)out         + (size_t)b * 4   * FT4 + (size_t)f * T4 + t4;

    // Skip channels (issued early; consumed in conv2) — non-temporal, zero reuse
    float4 s0 = ntload4(xs4);
    float4 s1 = ntload4(xs4 + FT4);
    float4 s2 = ntload4(xs4 + 2 * FT4);
    float4 s3 = ntload4(xs4 + 3 * FT4);

    // Rolling 8-deep prefetch ring: keeps ~8 loads continuously outstanding
    float4 buf[8];
    #pragma unroll
    for (int j = 0; j < 8; ++j) buf[j] = ntload4(xd4 + (size_t)j * FT4);

    // conv1: h[o] = relu(b1[o] + sum_c W1[o,c] * xd[c])
    float4 h[11];
    #pragma unroll
    for (int o = 0; o < 11; ++o) h[o] = f4(b1[o]);   // uniform scalar reads

    // c = 0..55: consume buf[c&7], immediately refill with c+8 (static ring indices)
    #pragma unroll 8
    for (int c = 0; c < 56; ++c) {
        float4 x = buf[c & 7];
        buf[c & 7] = ntload4(xd4 + (size_t)(c + 8) * FT4);
        C1STEP(c, x)
    }
    // c = 56..63: drain
    #pragma unroll
    for (int c = 56; c < 64; ++c) {
        float4 x = buf[c & 7];
        C1STEP(c, x)
    }

    #pragma unroll
    for (int o = 0; o < 11; ++o) h[o] = relu4(h[o]);

    // conv2: out[o] = b2[o] + sum_{c<4} W2[o,c]*skip[c] + sum_j W2[o,4+j]*h[j]
    float4 o2[11];
    #pragma unroll
    for (int o = 0; o < 11; ++o) o2[o] = f4(b2[o]);  // uniform scalar reads

    // Weights via lane-uniform W2[o*15 + cidx] -> s_load, SGPR operand
#define W2COL(cidx, xvec)                                                         \
    {                                                                             \
        fma4(o2[0],  W2[0 * 15 + (cidx)], (xvec));                                \
        fma4(o2[1],  W2[1 * 15 + (cidx)], (xvec));                                \
        fma4(o2[2],  W2[2 * 15 + (cidx)], (xvec));                                \
        fma4(o2[3],  W2[3 * 15 + (cidx)], (xvec));                                \
        fma4(o2[4],  W2[4 * 15 + (cidx)], (xvec));                                \
        fma4(o2[5],  W2[5 * 15 + (cidx)], (xvec));                                \
        fma4(o2[6],  W2[6 * 15 + (cidx)], (xvec));                                \
        fma4(o2[7],  W2[7 * 15 + (cidx)], (xvec));                                \
        fma4(o2[8],  W2[8 * 15 + (cidx)], (xvec));                                \
        fma4(o2[9],  W2[9 * 15 + (cidx)], (xvec));                                \
        fma4(o2[10], W2[10 * 15 + (cidx)], (xvec));                               \
    }

    W2COL(0, s0)
    W2COL(1, s1)
    W2COL(2, s2)
    W2COL(3, s3)
    #pragma unroll
    for (int j = 0; j < 11; ++j) W2COL(4 + j, h[j])
#undef W2COL

    // activations + grouped contraction
    float4 m0 = sigm4(o2[9]);
    float4 m1 = sigm4(o2[10]);

    float4 y0 = mul4(m0, fma44(ssign4(o2[0]), s0, fma44(ssign4(o2[1]), s1, mul4(ssign4(o2[2]), s2))));
    float4 y1 = mul4(m0, fma44(ssign4(o2[3]), s0, fma44(ssign4(o2[4]), s1, mul4(ssign4(o2[5]), s2))));
    float4 y2 = mul4(m0, fma44(ssign4(o2[6]), s0, fma44(ssign4(o2[7]), s1, mul4(ssign4(o2[8]), s2))));
    float4 y3 = mul4(m1, s3);

    ntstore4(o4,           y0);
    ntstore4(o4 + FT4,     y1);
    ntstore4(o4 + 2 * FT4, y2);
    ntstore4(o4 + 3 * FT4, y3);
}

extern "C" void kernel_launch(void* const* d_in, const int* in_sizes, int n_in,
                              void* d_out, int out_size, void* d_ws, size_t ws_size,
                              hipStream_t stream) {
    const float* xdec  = (const float*)d_in[0];
    const float* xskip = (const float*)d_in[1];
    const float* W1    = (const float*)d_in[2];
    const float* b1    = (const float*)d_in[3];
    const float* W2    = (const float*)d_in[4];
    const float* b2    = (const float*)d_in[5];
    float* outp = (float*)d_out;

    const int total_v = BB * NF * T4;      // 526336
    const int blocks  = total_v / 256;     // 2056 exact
    outconv_fused<<<blocks, 256, 0, stream>>>(xdec, xskip, W1, b1, W2, b2, outp);
}

// Round 9
// 109.985 us; speedup vs baseline: 1.8911x; 1.0128x over previous
//
#include <hip/hip_runtime.h>

// Problem constants (compile-time)
#define BB   16
#define CIN  64
#define NF   257
#define NT   512
#define T4   (NT/4)          // 128 float4 per row
#define FT4  (NF*T4)         // 32896 float4 per channel plane

typedef float v4f __attribute__((ext_vector_type(4)));

__device__ __forceinline__ float4 ntload4(const float4* p) {
    v4f v = __builtin_nontemporal_load((const v4f*)p);
    return make_float4(v.x, v.y, v.z, v.w);
}
__device__ __forceinline__ void ntstore4(float4* p, float4 val) {
    v4f v;
    v.x = val.x; v.y = val.y; v.z = val.z; v.w = val.w;
    __builtin_nontemporal_store(v, (v4f*)p);
}

__device__ __forceinline__ float4 f4(float v) { return make_float4(v, v, v, v); }

__device__ __forceinline__ void fma4(float4& a, float w, const float4& x) {
    a.x = fmaf(w, x.x, a.x); a.y = fmaf(w, x.y, a.y);
    a.z = fmaf(w, x.z, a.z); a.w = fmaf(w, x.w, a.w);
}
__device__ __forceinline__ float4 relu4(float4 a) {
    return make_float4(fmaxf(a.x, 0.f), fmaxf(a.y, 0.f), fmaxf(a.z, 0.f), fmaxf(a.w, 0.f));
}
__device__ __forceinline__ float ssign1(float x) { return x / (1.f + fabsf(x)); }
__device__ __forceinline__ float4 ssign4(float4 a) {
    return make_float4(ssign1(a.x), ssign1(a.y), ssign1(a.z), ssign1(a.w));
}
__device__ __forceinline__ float sigm1(float x) { return 1.f / (1.f + __expf(-x)); }
__device__ __forceinline__ float4 sigm4(float4 a) {
    return make_float4(sigm1(a.x), sigm1(a.y), sigm1(a.z), sigm1(a.w));
}
__device__ __forceinline__ float4 mul4(float4 a, float4 b) {
    return make_float4(a.x * b.x, a.y * b.y, a.z * b.z, a.w * b.w);
}
__device__ __forceinline__ float4 fma44(float4 a, float4 b, float4 c) {
    return make_float4(fmaf(a.x, b.x, c.x), fmaf(a.y, b.y, c.y),
                       fmaf(a.z, b.z, c.z), fmaf(a.w, b.w, c.w));
}

// One FMA block of conv1 for channel c with input vector x.
// Weights read via lane-uniform addresses -> scalar loads (s_load), SGPR operands.
#define C1STEP(c, x)                                                              \
    {                                                                             \
        fma4(h[0],  W1[0 * CIN + (c)], (x));                                      \
        fma4(h[1],  W1[1 * CIN + (c)], (x));                                      \
        fma4(h[2],  W1[2 * CIN + (c)], (x));                                      \
        fma4(h[3],  W1[3 * CIN + (c)], (x));                                      \
        fma4(h[4],  W1[4 * CIN + (c)], (x));                                      \
        fma4(h[5],  W1[5 * CIN + (c)], (x));                                      \
        fma4(h[6],  W1[6 * CIN + (c)], (x));                                      \
        fma4(h[7],  W1[7 * CIN + (c)], (x));                                      \
        fma4(h[8],  W1[8 * CIN + (c)], (x));                                      \
        fma4(h[9],  W1[9 * CIN + (c)], (x));                                      \
        fma4(h[10], W1[10 * CIN + (c)], (x));                                     \
    }

__global__ __launch_bounds__(256) void outconv_fused(
    const float* __restrict__ xdec,   // [B,64,F,T]
    const float* __restrict__ xskip,  // [B,4,F,T]
    const float* __restrict__ W1,     // [11,64]
    const float* __restrict__ b1,     // [11]
    const float* __restrict__ W2,     // [11,15]
    const float* __restrict__ b2,     // [11]
    float* __restrict__ out)          // [B,4,F,T]
{
    const int v  = blockIdx.x * 256 + threadIdx.x;  // float4-pixel index
    const int t4 = v & (T4 - 1);
    const int bf = v >> 7;          // b*NF + f
    const int f  = bf % NF;
    const int b  = bf / NF;

    const float4* xd4 = (const float4*)xdec  + (size_t)b * CIN * FT4 + (size_t)f * T4 + t4;
    const float4* xs4 = (const float4*)xskip + (size_t)b * 4   * FT4 + (size_t)f * T4 + t4;
    float4*       o4  = (float4*)out         + (size_t)b * 4   * FT4 + (size_t)f * T4 + t4;

    // Skip channels (issued early; consumed in conv2) — non-temporal, zero reuse
    float4 s0 = ntload4(xs4);
    float4 s1 = ntload4(xs4 + FT4);
    float4 s2 = ntload4(xs4 + 2 * FT4);
    float4 s3 = ntload4(xs4 + 3 * FT4);

    // Rolling 4-deep prefetch ring (VGPR-lean; depth still covers HBM latency)
    float4 buf[4];
    #pragma unroll
    for (int j = 0; j < 4; ++j) buf[j] = ntload4(xd4 + (size_t)j * FT4);

    // conv1: h[o] = relu(b1[o] + sum_c W1[o,c] * xd[c])
    float4 h[11];
    #pragma unroll
    for (int o = 0; o < 11; ++o) h[o] = f4(b1[o]);   // uniform scalar reads

    // c = 0..59: consume buf[c&3], immediately refill with c+4 (static ring indices)
    #pragma unroll 4
    for (int c = 0; c < 60; ++c) {
        float4 x = buf[c & 3];
        buf[c & 3] = ntload4(xd4 + (size_t)(c + 4) * FT4);
        C1STEP(c, x)
    }
    // c = 60..63: drain
    #pragma unroll
    for (int c = 60; c < 64; ++c) {
        float4 x = buf[c & 3];
        C1STEP(c, x)
    }

    #pragma unroll
    for (int o = 0; o < 11; ++o) h[o] = relu4(h[o]);

    // conv2: out[o] = b2[o] + sum_{c<4} W2[o,c]*skip[c] + sum_j W2[o,4+j]*h[j]
    float4 o2[11];
    #pragma unroll
    for (int o = 0; o < 11; ++o) o2[o] = f4(b2[o]);  // uniform scalar reads

    // Weights via lane-uniform W2[o*15 + cidx] -> s_load, SGPR operand
#define W2COL(cidx, xvec)                                                         \
    {                                                                             \
        fma4(o2[0],  W2[0 * 15 + (cidx)], (xvec));                                \
        fma4(o2[1],  W2[1 * 15 + (cidx)], (xvec));                                \
        fma4(o2[2],  W2[2 * 15 + (cidx)], (xvec));                                \
        fma4(o2[3],  W2[3 * 15 + (cidx)], (xvec));                                \
        fma4(o2[4],  W2[4 * 15 + (cidx)], (xvec));                                \
        fma4(o2[5],  W2[5 * 15 + (cidx)], (xvec));                                \
        fma4(o2[6],  W2[6 * 15 + (cidx)], (xvec));                                \
        fma4(o2[7],  W2[7 * 15 + (cidx)], (xvec));                                \
        fma4(o2[8],  W2[8 * 15 + (cidx)], (xvec));                                \
        fma4(o2[9],  W2[9 * 15 + (cidx)], (xvec));                                \
        fma4(o2[10], W2[10 * 15 + (cidx)], (xvec));                               \
    }

    W2COL(0, s0)
    W2COL(1, s1)
    W2COL(2, s2)
    W2COL(3, s3)
    #pragma unroll
    for (int j = 0; j < 11; ++j) W2COL(4 + j, h[j])
#undef W2COL

    // activations + grouped contraction
    float4 m0 = sigm4(o2[9]);
    float4 m1 = sigm4(o2[10]);

    float4 y0 = mul4(m0, fma44(ssign4(o2[0]), s0, fma44(ssign4(o2[1]), s1, mul4(ssign4(o2[2]), s2))));
    float4 y1 = mul4(m0, fma44(ssign4(o2[3]), s0, fma44(ssign4(o2[4]), s1, mul4(ssign4(o2[5]), s2))));
    float4 y2 = mul4(m0, fma44(ssign4(o2[6]), s0, fma44(ssign4(o2[7]), s1, mul4(ssign4(o2[8]), s2))));
    float4 y3 = mul4(m1, s3);

    ntstore4(o4,           y0);
    ntstore4(o4 + FT4,     y1);
    ntstore4(o4 + 2 * FT4, y2);
    ntstore4(o4 + 3 * FT4, y3);
}

extern "C" void kernel_launch(void* const* d_in, const int* in_sizes, int n_in,
                              void* d_out, int out_size, void* d_ws, size_t ws_size,
                              hipStream_t stream) {
    const float* xdec  = (const float*)d_in[0];
    const float* xskip = (const float*)d_in[1];
    const float* W1    = (const float*)d_in[2];
    const float* b1    = (const float*)d_in[3];
    const float* W2    = (const float*)d_in[4];
    const float* b2    = (const float*)d_in[5];
    float* outp = (float*)d_out;

    const int total_v = BB * NF * T4;      // 526336
    const int blocks  = total_v / 256;     // 2056 exact
    outconv_fused<<<blocks, 256, 0, stream>>>(xdec, xskip, W1, b1, W2, b2, outp);
}